// Round 2
// baseline (365.838 us; speedup 1.0000x reference)
//
#include <hip/hip_runtime.h>
#include <hip/hip_bf16.h>

typedef __bf16 bf16x8 __attribute__((ext_vector_type(8)));
typedef float  f32x4  __attribute__((ext_vector_type(4)));

#define MFMA16(a, b, c) __builtin_amdgcn_mfma_f32_16x16x32_bf16((a), (b), (c), 0, 0, 0)

// ---------------------------------------------------------------------------
// K0: exclusive scan of sizes[8192] -> offsets[8192].
// ---------------------------------------------------------------------------
__global__ void k_scan(const int* __restrict__ sizes, int* __restrict__ offsets) {
  __shared__ int part[256];
  const int t = threadIdx.x;
  const int base = t * 32;
  int v[32];
  int s = 0;
#pragma unroll
  for (int i = 0; i < 32; ++i) { v[i] = sizes[base + i]; s += v[i]; }
  part[t] = s;
  __syncthreads();
  for (int d = 1; d < 256; d <<= 1) {
    int add = (t >= d) ? part[t - d] : 0;
    __syncthreads();
    part[t] += add;
    __syncthreads();
  }
  int run = (t == 0) ? 0 : part[t - 1];
#pragma unroll
  for (int i = 0; i < 32; ++i) { offsets[base + i] = run; run += v[i]; }
}

// ---------------------------------------------------------------------------
// K1: pack conv weights (6 K=128 slices, single bf16) and lin_w (hi/lo pair)
// into MFMA B-fragment order.
// B-frag for 16x16x32: lane holds B[k = (lane>>4)*8 + j][n = lane&15], j=0..7.
// ---------------------------------------------------------------------------
__global__ void k_pack(const float* __restrict__ w0, const float* __restrict__ w1,
                       const float* __restrict__ w2, const float* __restrict__ lw,
                       __bf16* __restrict__ Wpack,
                       __bf16* __restrict__ Lhi, __bf16* __restrict__ Llo) {
  const int bid = blockIdx.x, t = threadIdx.x;
  if (bid < 48) {
    const int nt = bid, sl = nt >> 3, f = nt & 7;
    const int kt = t >> 6, lane = t & 63;
    const float* src; int kw, jj;
    if      (sl == 0) { src = w0; kw = 1; jj = 0; }
    else if (sl == 1) { src = w1; kw = 2; jj = 0; }
    else if (sl == 2) { src = w1; kw = 2; jj = 1; }
    else if (sl == 3) { src = w2; kw = 3; jj = 0; }
    else if (sl == 4) { src = w2; kw = 3; jj = 1; }
    else              { src = w2; kw = 3; jj = 2; }
    const int feat  = f * 16 + (lane & 15);
    const int cbase = kt * 32 + ((lane >> 4) << 3);
    __bf16* dst = Wpack + ((((nt * 4 + kt) << 6) + lane) << 3);
#pragma unroll
    for (int j = 0; j < 8; ++j)
      dst[j] = (__bf16)src[(feat * 128 + cbase + j) * kw + jj];
  } else {
    const int idx = (bid - 48) * 256 + t;          // 0..49151
    const int j = idx & 7, lane = (idx >> 3) & 63, rest = idx >> 9;  // 0..95
    const int kt = rest % 12, nt = rest / 12;
    const int o = nt * 16 + (lane & 15);
    const int q = kt * 32 + ((lane >> 4) << 3) + j;
    const float v = lw[o * 384 + q];
    const __bf16 hi = (__bf16)v;
    Lhi[idx] = hi;
    Llo[idx] = (__bf16)(v - (float)hi);
  }
}

// ---------------------------------------------------------------------------
// K2: fused conv (6 slices via MFMA, split-x hi/lo) + shifted combine + relu
// + ragged max.  One block per segment.  Pooled outputs stored as bf16 hi/lo.
// C/D layout (m89-verified): col = lane&15, row = (lane>>4)*4 + reg.
// ---------------------------------------------------------------------------
__global__ __launch_bounds__(256, 3)
void k_conv(const float* __restrict__ x, const int* __restrict__ sizes,
            const int* __restrict__ offsets,
            const float* __restrict__ cb0, const float* __restrict__ cb1,
            const float* __restrict__ cb2,
            const bf16x8* __restrict__ Wpack,
            __bf16* __restrict__ Phi, __bf16* __restrict__ Plo) {
  __shared__ __bf16 xh[64 * 136];   // [row][128 + 8 pad] bf16 hi
  __shared__ __bf16 xl[64 * 136];   // lo residual
  const int b = blockIdx.x;
  const int s = sizes[b];
  const long off = offsets[b];
  const int t = threadIdx.x;
  const int MT = (s + 15) >> 4;

  // ---- stage x rows [0,s): f32 -> bf16 hi/lo into LDS ----
  const int quads = s << 5;                       // s*128/4
  for (int qi = t; qi < quads; qi += 256) {
    const int e = qi << 2, r = e >> 7, c = e & 127;
    const float4 v = *(const float4*)(x + (off + r) * 128 + c);
    __bf16* dh = &xh[r * 136 + c];
    __bf16* dl = &xl[r * 136 + c];
    dh[0] = (__bf16)v.x; dl[0] = (__bf16)(v.x - (float)dh[0]);
    dh[1] = (__bf16)v.y; dl[1] = (__bf16)(v.y - (float)dh[1]);
    dh[2] = (__bf16)v.z; dl[2] = (__bf16)(v.z - (float)dh[2]);
    dh[3] = (__bf16)v.w; dl[3] = (__bf16)(v.w - (float)dh[3]);
  }
  // zero-fill pad rows [s, MT*16)
  const int padquads = ((MT << 4) - s) << 5;
  for (int qi = t; qi < padquads; qi += 256) {
    const int e = (qi << 2) + (s << 7), r = e >> 7, c = e & 127;
    __bf16* dh = &xh[r * 136 + c];
    __bf16* dl = &xl[r * 136 + c];
#pragma unroll
    for (int j = 0; j < 4; ++j) { dh[j] = (__bf16)0.f; dl[j] = (__bf16)0.f; }
  }
  __syncthreads();

  const int wid = t >> 6, lane = t & 63;
  const int lo16 = lane & 15, g = lane >> 4;

#pragma unroll
  for (int fi = 0; fi < 2; ++fi) {
    const int ft = wid + (fi << 2);
    const int feat = ft * 16 + lo16;
#pragma unroll
    for (int pass = 0; pass < 2; ++pass) {
      // pass 0: slices 0,1,2 = Y_w1j0, Y_w2j0, Y_w2j1  -> pools 1,2
      // pass 1: slices 3,4,5 = Y_w3j0, Y_w3j1, Y_w3j2  -> pool 3
      f32x4 acc[4][3];
#pragma unroll
      for (int mt = 0; mt < 4; ++mt)
#pragma unroll
        for (int sl = 0; sl < 3; ++sl)
          acc[mt][sl] = f32x4{0.f, 0.f, 0.f, 0.f};

#pragma unroll
      for (int kt = 0; kt < 4; ++kt) {
        bf16x8 bf[3];
#pragma unroll
        for (int sl = 0; sl < 3; ++sl) {
          const int slg = pass * 3 + sl;
          bf[sl] = Wpack[(((slg * 8 + ft) * 4 + kt) << 6) + lane];
        }
#pragma unroll
        for (int mt = 0; mt < 4; ++mt) {
          if (mt < MT) {   // uniform per block
            const int aoff = (mt * 16 + lo16) * 136 + kt * 32 + (g << 3);
            const bf16x8 ah = *(const bf16x8*)&xh[aoff];
            const bf16x8 al = *(const bf16x8*)&xl[aoff];
            acc[mt][0] = MFMA16(ah, bf[0], acc[mt][0]);
            acc[mt][1] = MFMA16(ah, bf[1], acc[mt][1]);
            acc[mt][2] = MFMA16(ah, bf[2], acc[mt][2]);
            acc[mt][0] = MFMA16(al, bf[0], acc[mt][0]);
            acc[mt][1] = MFMA16(al, bf[1], acc[mt][1]);
            acc[mt][2] = MFMA16(al, bf[2], acc[mt][2]);
          }
        }
      }

      if (pass == 0) {
        float m1 = -1e30f, m2 = -1e30f;
#pragma unroll
        for (int mt = 0; mt < 4; ++mt) {
          if (mt >= MT) continue;  // uniform
#pragma unroll
          for (int v = 0; v < 4; ++v) {
            // Y_w2j1 shifted by +1 row
            float s2v;
            if (v < 3) {
              s2v = acc[mt][2][v + 1];
            } else {
              const float up = __shfl(acc[mt][2][0], lane + 16);
              const float dn = __shfl(acc[(mt < 3) ? mt + 1 : mt][2][0], lo16);
              s2v = (g < 3) ? up : dn;
            }
            const int lrow = mt * 16 + g * 4 + v;
            if (lrow < s)     m1 = fmaxf(m1, acc[mt][0][v]);
            if (lrow < s - 1) m2 = fmaxf(m2, acc[mt][1][v] + s2v);
          }
        }
        m1 = fmaxf(m1, __shfl_xor(m1, 16)); m1 = fmaxf(m1, __shfl_xor(m1, 32));
        m2 = fmaxf(m2, __shfl_xor(m2, 16)); m2 = fmaxf(m2, __shfl_xor(m2, 32));
        if (g == 0) {
          // max(relu(h)) == relu(max(Y)+b): bias row-constant, relu monotone
          const float p1 = fmaxf(m1 + cb0[feat], 0.f);
          const float p2 = fmaxf(m2 + cb1[feat], 0.f);
          const __bf16 h1 = (__bf16)p1, h2 = (__bf16)p2;
          Phi[(long)b * 384 + feat]       = h1;
          Plo[(long)b * 384 + feat]       = (__bf16)(p1 - (float)h1);
          Phi[(long)b * 384 + 128 + feat] = h2;
          Plo[(long)b * 384 + 128 + feat] = (__bf16)(p2 - (float)h2);
        }
      } else {
        float m3 = -1e30f;
#pragma unroll
        for (int mt = 0; mt < 4; ++mt) {
          if (mt >= MT) continue;  // uniform
#pragma unroll
          for (int v = 0; v < 4; ++v) {
            float s4v, s5v;
            if (v < 3) {
              s4v = acc[mt][1][v + 1];
            } else {
              const float up = __shfl(acc[mt][1][0], lane + 16);
              const float dn = __shfl(acc[(mt < 3) ? mt + 1 : mt][1][0], lo16);
              s4v = (g < 3) ? up : dn;
            }
            if (v < 2) {
              s5v = acc[mt][2][v + 2];
            } else {
              const float up = __shfl(acc[mt][2][v - 2], lane + 16);
              const float dn = __shfl(acc[(mt < 3) ? mt + 1 : mt][2][v - 2], lo16);
              s5v = (g < 3) ? up : dn;
            }
            const int lrow = mt * 16 + g * 4 + v;
            if (lrow < s - 2) m3 = fmaxf(m3, acc[mt][0][v] + s4v + s5v);
          }
        }
        m3 = fmaxf(m3, __shfl_xor(m3, 16)); m3 = fmaxf(m3, __shfl_xor(m3, 32));
        if (g == 0) {
          const float p3 = fmaxf(m3 + cb2[feat], 0.f);
          const __bf16 h3 = (__bf16)p3;
          Phi[(long)b * 384 + 256 + feat] = h3;
          Plo[(long)b * 384 + 256 + feat] = (__bf16)(p3 - (float)h3);
        }
      }
    }
  }
}

// ---------------------------------------------------------------------------
// K3: out = tanh(P[8192,384] @ lin_w^T + lin_b), split bf16 MFMA (3 products:
// Ph*Wh + Pl*Wh + Ph*Wl -> ~fp32 accuracy).  256 blocks x 32 batch rows.
// ---------------------------------------------------------------------------
__global__ __launch_bounds__(256, 2)
void k_lin(const __bf16* __restrict__ Phi, const __bf16* __restrict__ Plo,
           const bf16x8* __restrict__ Lhi, const bf16x8* __restrict__ Llo,
           const float* __restrict__ lb, float* __restrict__ out) {
  __shared__ __bf16 ph[32 * 392];   // [row][384 + 8 pad]
  __shared__ __bf16 pl[32 * 392];
  const int blk = blockIdx.x, t = threadIdx.x;
  const long rbase = (long)blk * 32;
  // stage 32 rows x 384 bf16 (hi and lo) = 1536 16-byte chunks each
#pragma unroll
  for (int i = 0; i < 6; ++i) {
    const int ci = t + (i << 8);
    const int r = ci / 48, cc = ci % 48;
    *(int4*)&ph[r * 392 + (cc << 3)] = *(const int4*)&Phi[(rbase + r) * 384 + (cc << 3)];
    *(int4*)&pl[r * 392 + (cc << 3)] = *(const int4*)&Plo[(rbase + r) * 384 + (cc << 3)];
  }
  __syncthreads();
  const int wid = t >> 6, lane = t & 63;
  const int lo16 = lane & 15, g = lane >> 4;
#pragma unroll
  for (int ni = 0; ni < 2; ++ni) {
    const int nt = wid + (ni << 2);
    f32x4 acc[2];
    acc[0] = f32x4{0.f, 0.f, 0.f, 0.f};
    acc[1] = f32x4{0.f, 0.f, 0.f, 0.f};
#pragma unroll
    for (int kt = 0; kt < 12; ++kt) {
      const bf16x8 bh = Lhi[((nt * 12 + kt) << 6) + lane];
      const bf16x8 bl = Llo[((nt * 12 + kt) << 6) + lane];
#pragma unroll
      for (int mt = 0; mt < 2; ++mt) {
        const int aoff = (mt * 16 + lo16) * 392 + kt * 32 + (g << 3);
        const bf16x8 ah = *(const bf16x8*)&ph[aoff];
        const bf16x8 al = *(const bf16x8*)&pl[aoff];
        acc[mt] = MFMA16(ah, bh, acc[mt]);
        acc[mt] = MFMA16(al, bh, acc[mt]);
        acc[mt] = MFMA16(ah, bl, acc[mt]);
      }
    }
    const int o = nt * 16 + lo16;
    const float bias = lb[o];
#pragma unroll
    for (int mt = 0; mt < 2; ++mt)
#pragma unroll
      for (int v = 0; v < 4; ++v) {
        const int r = mt * 16 + g * 4 + v;
        const float val = acc[mt][v] + bias;
        out[(rbase + r) * 128 + o] = 1.f - 2.f / (__expf(2.f * val) + 1.f);
      }
  }
}

// ---------------------------------------------------------------------------
extern "C" void kernel_launch(void* const* d_in, const int* in_sizes, int n_in,
                              void* d_out, int out_size, void* d_ws, size_t ws_size,
                              hipStream_t stream) {
  const float* x   = (const float*)d_in[0];
  const int* sizes = (const int*)d_in[1];
  const float* w0  = (const float*)d_in[2];
  const float* cb0 = (const float*)d_in[3];
  const float* w1  = (const float*)d_in[4];
  const float* cb1 = (const float*)d_in[5];
  const float* w2  = (const float*)d_in[6];
  const float* cb2 = (const float*)d_in[7];
  const float* lw  = (const float*)d_in[8];
  const float* lb  = (const float*)d_in[9];

  char* ws = (char*)d_ws;
  size_t o = 0;
  int*    offsets = (int*)ws;                 o += 32768;
  __bf16* Wpack   = (__bf16*)(ws + o);        o += 196608;     // 48*4*64*8*2
  __bf16* Lhi     = (__bf16*)(ws + o);        o += 98304;      // 8*12*64*8*2
  __bf16* Llo     = (__bf16*)(ws + o);        o += 98304;
  __bf16* Phi     = (__bf16*)(ws + o);        o += 8192L * 384 * 2;
  __bf16* Plo     = (__bf16*)(ws + o);        o += 8192L * 384 * 2;

  k_scan<<<1, 256, 0, stream>>>(sizes, offsets);
  k_pack<<<240, 256, 0, stream>>>(w0, w1, w2, lw, Wpack, Lhi, Llo);
  k_conv<<<8192, 256, 0, stream>>>(x, sizes, offsets, cb0, cb1, cb2,
                                   (const bf16x8*)Wpack, Phi, Plo);
  k_lin<<<256, 256, 0, stream>>>(Phi, Plo, (const bf16x8*)Lhi,
                                 (const bf16x8*)Llo, lb, (float*)d_out);
}

// Round 3
// 340.867 us; speedup vs baseline: 1.0733x; 1.0733x over previous
//
#include <hip/hip_runtime.h>
#include <hip/hip_bf16.h>

typedef __bf16 bf16x8 __attribute__((ext_vector_type(8)));
typedef __bf16 bf16x4 __attribute__((ext_vector_type(4)));
typedef float  f32x4  __attribute__((ext_vector_type(4)));

#define MFMA16(a, b, c) __builtin_amdgcn_mfma_f32_16x16x32_bf16((a), (b), (c), 0, 0, 0)

// ---------------------------------------------------------------------------
// K1: block 240: exclusive scan of sizes; blocks 0-47: conv weight pack;
// blocks 48-239: lin_w hi/lo pack.
// B-frag for 16x16x32: lane holds B[k = (lane>>4)*8 + j][n = lane&15], j=0..7.
// ---------------------------------------------------------------------------
__global__ void k_prep(const int* __restrict__ sizes, int* __restrict__ offsets,
                       const float* __restrict__ w0, const float* __restrict__ w1,
                       const float* __restrict__ w2, const float* __restrict__ lw,
                       __bf16* __restrict__ Wpack,
                       __bf16* __restrict__ Lhi, __bf16* __restrict__ Llo) {
  const int bid = blockIdx.x, t = threadIdx.x;
  if (bid == 240) {
    __shared__ int part[256];
    const int base = t * 32;
    int v[32];
    int s = 0;
#pragma unroll
    for (int i = 0; i < 32; ++i) { v[i] = sizes[base + i]; s += v[i]; }
    part[t] = s;
    __syncthreads();
    for (int d = 1; d < 256; d <<= 1) {
      int add = (t >= d) ? part[t - d] : 0;
      __syncthreads();
      part[t] += add;
      __syncthreads();
    }
    int run = (t == 0) ? 0 : part[t - 1];
#pragma unroll
    for (int i = 0; i < 32; ++i) { offsets[base + i] = run; run += v[i]; }
  } else if (bid < 48) {
    const int nt = bid, sl = nt >> 3, f = nt & 7;
    const int kt = t >> 6, lane = t & 63;
    const float* src; int kw, jj;
    if      (sl == 0) { src = w0; kw = 1; jj = 0; }
    else if (sl == 1) { src = w1; kw = 2; jj = 0; }
    else if (sl == 2) { src = w1; kw = 2; jj = 1; }
    else if (sl == 3) { src = w2; kw = 3; jj = 0; }
    else if (sl == 4) { src = w2; kw = 3; jj = 1; }
    else              { src = w2; kw = 3; jj = 2; }
    const int feat  = f * 16 + (lane & 15);
    const int cbase = kt * 32 + ((lane >> 4) << 3);
    __bf16* dst = Wpack + ((((nt * 4 + kt) << 6) + lane) << 3);
#pragma unroll
    for (int j = 0; j < 8; ++j)
      dst[j] = (__bf16)src[(feat * 128 + cbase + j) * kw + jj];
  } else {
    const int idx = (bid - 48) * 256 + t;          // 0..49151
    const int j = idx & 7, lane = (idx >> 3) & 63, rest = idx >> 9;  // 0..95
    const int kt = rest % 12, nt = rest / 12;
    const int o = nt * 16 + (lane & 15);
    const int q = kt * 32 + ((lane >> 4) << 3) + j;
    const float v = lw[o * 384 + q];
    const __bf16 hi = (__bf16)v;
    Lhi[idx] = hi;
    Llo[idx] = (__bf16)(v - (float)hi);
  }
}

// ---------------------------------------------------------------------------
// K2: fused conv (6 slices via MFMA, single-pass) + shifted combine + relu
// + ragged max.  One block per segment; x staged as single bf16 (hi).
// C/D layout (m89-verified): col = lane&15, row = (lane>>4)*4 + reg.
// ---------------------------------------------------------------------------
__global__ __launch_bounds__(256, 3)
void k_conv(const float* __restrict__ x, const int* __restrict__ sizes,
            const int* __restrict__ offsets,
            const float* __restrict__ cb0, const float* __restrict__ cb1,
            const float* __restrict__ cb2,
            const bf16x8* __restrict__ Wpack,
            __bf16* __restrict__ Phi, __bf16* __restrict__ Plo) {
  __shared__ __bf16 xh[64 * 136];   // [row][128 + 8 pad] bf16, 17.4 KB
  const int b = blockIdx.x;
  const int s = sizes[b];
  const long off = offsets[b];
  const int t = threadIdx.x;
  const int MT = (s + 15) >> 4;

  // ---- stage x rows [0,s): f32 -> bf16 into LDS (float4 loads, b64 stores)
  const int quads = s << 5;                       // s*128/4
  for (int qi = t; qi < quads; qi += 256) {
    const int e = qi << 2, r = e >> 7, c = e & 127;
    const float4 v = *(const float4*)(x + (off + r) * 128 + c);
    bf16x4 h; h[0] = (__bf16)v.x; h[1] = (__bf16)v.y;
              h[2] = (__bf16)v.z; h[3] = (__bf16)v.w;
    *(bf16x4*)&xh[r * 136 + c] = h;
  }
  // zero-fill pad rows [s, MT*16)
  const int padquads = ((MT << 4) - s) << 5;
  for (int qi = t; qi < padquads; qi += 256) {
    const int e = (qi << 2) + (s << 7), r = e >> 7, c = e & 127;
    *(bf16x4*)&xh[r * 136 + c] = bf16x4{(__bf16)0.f, (__bf16)0.f, (__bf16)0.f, (__bf16)0.f};
  }
  __syncthreads();

  const int wid = t >> 6, lane = t & 63;
  const int lo16 = lane & 15, g = lane >> 4;

#pragma unroll
  for (int fi = 0; fi < 2; ++fi) {
    const int ft = wid + (fi << 2);
    const int feat = ft * 16 + lo16;
    // slices: 0 = w1j0 (pool1); 1,2 = w2j0,w2j1 (pool2); 3,4,5 = w3j0,j1,j2 (pool3)
    f32x4 acc[4][6];
#pragma unroll
    for (int mt = 0; mt < 4; ++mt)
#pragma unroll
      for (int sl = 0; sl < 6; ++sl)
        acc[mt][sl] = f32x4{0.f, 0.f, 0.f, 0.f};

#pragma unroll
    for (int kt = 0; kt < 4; ++kt) {
      bf16x8 bf[6];
#pragma unroll
      for (int sl = 0; sl < 6; ++sl)
        bf[sl] = Wpack[(((sl * 8 + ft) * 4 + kt) << 6) + lane];
#pragma unroll
      for (int mt = 0; mt < 4; ++mt) {
        if (mt < MT) {   // uniform per block
          const bf16x8 a =
              *(const bf16x8*)&xh[(mt * 16 + lo16) * 136 + kt * 32 + (g << 3)];
#pragma unroll
          for (int sl = 0; sl < 6; ++sl)
            acc[mt][sl] = MFMA16(a, bf[sl], acc[mt][sl]);
        }
      }
    }

    float m1 = -1e30f, m2 = -1e30f, m3 = -1e30f;
#pragma unroll
    for (int mt = 0; mt < 4; ++mt) {
      if (mt >= MT) continue;  // uniform
#pragma unroll
      for (int v = 0; v < 4; ++v) {
        // +1-row shift of slice 2 (pool2)
        float s2v;
        if (v < 3) {
          s2v = acc[mt][2][v + 1];
        } else {
          const float up = __shfl(acc[mt][2][0], lane + 16);
          const float dn = __shfl(acc[(mt < 3) ? mt + 1 : mt][2][0], lo16);
          s2v = (g < 3) ? up : dn;
        }
        // +1-row shift of slice 4, +2-row shift of slice 5 (pool3)
        float s4v;
        if (v < 3) {
          s4v = acc[mt][4][v + 1];
        } else {
          const float up = __shfl(acc[mt][4][0], lane + 16);
          const float dn = __shfl(acc[(mt < 3) ? mt + 1 : mt][4][0], lo16);
          s4v = (g < 3) ? up : dn;
        }
        float s5v;
        if (v < 2) {
          s5v = acc[mt][5][v + 2];
        } else {
          const float up = __shfl(acc[mt][5][v - 2], lane + 16);
          const float dn = __shfl(acc[(mt < 3) ? mt + 1 : mt][5][v - 2], lo16);
          s5v = (g < 3) ? up : dn;
        }
        const int lrow = mt * 16 + g * 4 + v;
        if (lrow < s)     m1 = fmaxf(m1, acc[mt][0][v]);
        if (lrow < s - 1) m2 = fmaxf(m2, acc[mt][1][v] + s2v);
        if (lrow < s - 2) m3 = fmaxf(m3, acc[mt][3][v] + s4v + s5v);
      }
    }
    m1 = fmaxf(m1, __shfl_xor(m1, 16)); m1 = fmaxf(m1, __shfl_xor(m1, 32));
    m2 = fmaxf(m2, __shfl_xor(m2, 16)); m2 = fmaxf(m2, __shfl_xor(m2, 32));
    m3 = fmaxf(m3, __shfl_xor(m3, 16)); m3 = fmaxf(m3, __shfl_xor(m3, 32));
    if (g == 0) {
      // max(relu(h)) == relu(max(Y)+b): bias row-constant, relu monotone
      const float p1 = fmaxf(m1 + cb0[feat], 0.f);
      const float p2 = fmaxf(m2 + cb1[feat], 0.f);
      const float p3 = fmaxf(m3 + cb2[feat], 0.f);
      const __bf16 h1 = (__bf16)p1, h2 = (__bf16)p2, h3 = (__bf16)p3;
      Phi[(long)b * 384 + feat]       = h1;
      Plo[(long)b * 384 + feat]       = (__bf16)(p1 - (float)h1);
      Phi[(long)b * 384 + 128 + feat] = h2;
      Plo[(long)b * 384 + 128 + feat] = (__bf16)(p2 - (float)h2);
      Phi[(long)b * 384 + 256 + feat] = h3;
      Plo[(long)b * 384 + 256 + feat] = (__bf16)(p3 - (float)h3);
    }
  }
}

// ---------------------------------------------------------------------------
// K3: out = tanh(P[8192,384] @ lin_w^T + lin_b), split bf16 MFMA (3 products:
// Ph*Wh + Pl*Wh + Ph*Wl -> ~fp32 accuracy).  512 blocks x 16 batch rows.
// ---------------------------------------------------------------------------
__global__ __launch_bounds__(256, 4)
void k_lin(const __bf16* __restrict__ Phi, const __bf16* __restrict__ Plo,
           const bf16x8* __restrict__ Lhi, const bf16x8* __restrict__ Llo,
           const float* __restrict__ lb, float* __restrict__ out) {
  __shared__ __bf16 ph[16 * 392];   // [row][384 + 8 pad]
  __shared__ __bf16 pl[16 * 392];
  const int blk = blockIdx.x, t = threadIdx.x;
  const long rbase = (long)blk * 16;
  // stage 16 rows x 384 bf16 (hi and lo) = 768 16-byte chunks each
#pragma unroll
  for (int i = 0; i < 3; ++i) {
    const int ci = t + (i << 8);
    const int r = ci / 48, cc = ci % 48;
    *(int4*)&ph[r * 392 + (cc << 3)] = *(const int4*)&Phi[(rbase + r) * 384 + (cc << 3)];
    *(int4*)&pl[r * 392 + (cc << 3)] = *(const int4*)&Plo[(rbase + r) * 384 + (cc << 3)];
  }
  __syncthreads();
  const int wid = t >> 6, lane = t & 63;
  const int lo16 = lane & 15, g = lane >> 4;
#pragma unroll
  for (int ni = 0; ni < 2; ++ni) {
    const int nt = wid + (ni << 2);
    f32x4 acc = f32x4{0.f, 0.f, 0.f, 0.f};
#pragma unroll
    for (int kt = 0; kt < 12; ++kt) {
      const bf16x8 bh = Lhi[((nt * 12 + kt) << 6) + lane];
      const bf16x8 bl = Llo[((nt * 12 + kt) << 6) + lane];
      const int aoff = lo16 * 392 + kt * 32 + (g << 3);
      const bf16x8 ah = *(const bf16x8*)&ph[aoff];
      const bf16x8 al = *(const bf16x8*)&pl[aoff];
      acc = MFMA16(ah, bh, acc);
      acc = MFMA16(al, bh, acc);
      acc = MFMA16(ah, bl, acc);
    }
    const int o = nt * 16 + lo16;
    const float bias = lb[o];
#pragma unroll
    for (int v = 0; v < 4; ++v) {
      const int r = g * 4 + v;
      const float val = acc[v] + bias;
      out[(rbase + r) * 128 + o] = 1.f - 2.f / (__expf(2.f * val) + 1.f);
    }
  }
}

// ---------------------------------------------------------------------------
extern "C" void kernel_launch(void* const* d_in, const int* in_sizes, int n_in,
                              void* d_out, int out_size, void* d_ws, size_t ws_size,
                              hipStream_t stream) {
  const float* x   = (const float*)d_in[0];
  const int* sizes = (const int*)d_in[1];
  const float* w0  = (const float*)d_in[2];
  const float* cb0 = (const float*)d_in[3];
  const float* w1  = (const float*)d_in[4];
  const float* cb1 = (const float*)d_in[5];
  const float* w2  = (const float*)d_in[6];
  const float* cb2 = (const float*)d_in[7];
  const float* lw  = (const float*)d_in[8];
  const float* lb  = (const float*)d_in[9];

  char* ws = (char*)d_ws;
  size_t o = 0;
  int*    offsets = (int*)ws;                 o += 32768;
  __bf16* Wpack   = (__bf16*)(ws + o);        o += 196608;     // 48*4*64*8*2
  __bf16* Lhi     = (__bf16*)(ws + o);        o += 98304;      // 8*12*64*8*2
  __bf16* Llo     = (__bf16*)(ws + o);        o += 98304;
  __bf16* Phi     = (__bf16*)(ws + o);        o += 8192L * 384 * 2;
  __bf16* Plo     = (__bf16*)(ws + o);        o += 8192L * 384 * 2;

  k_prep<<<241, 256, 0, stream>>>(sizes, offsets, w0, w1, w2, lw, Wpack, Lhi, Llo);
  k_conv<<<8192, 256, 0, stream>>>(x, sizes, offsets, cb0, cb1, cb2,
                                   (const bf16x8*)Wpack, Phi, Plo);
  k_lin<<<512, 256, 0, stream>>>(Phi, Plo, (const bf16x8*)Lhi,
                                 (const bf16x8*)Llo, lb, (float*)d_out);
}